// Round 5
// baseline (195.836 us; speedup 1.0000x reference)
//
#include <hip/hip_runtime.h>

#define B_ 16
#define C_ 256
#define N_ 1024
#define NH 8
#define HD 32
#define KD 16
#define QKV_OUT_ 512
#define BN_EPS 1e-3f
// scale folded with 1/ln2 so softmax uses native exp2
#define SCALE2_ (0.25f * 1.44269504088896f)

typedef __attribute__((ext_vector_type(8))) short short8;
typedef __attribute__((ext_vector_type(16))) float float16;

__device__ inline unsigned short f2bf(float f) {
  unsigned int u = __float_as_uint(f);
  return (unsigned short)((u + 0x7FFF + ((u >> 16) & 1)) >> 16);  // RNE
}
__device__ inline float bf2f(unsigned short s) {
  return __uint_as_float(((unsigned int)s) << 16);
}
__device__ inline float16 zero16() {
  float16 z;
  #pragma unroll
  for (int i = 0; i < 16; ++i) z[i] = 0.f;
  return z;
}
// trunc pack (1 v_perm) -- used only for P (values in [0,~e^6], 0.4% rel err)
__device__ inline unsigned int pack_bf16_trunc(float a, float b) {
  return __builtin_amdgcn_perm(__float_as_uint(b), __float_as_uint(a), 0x07060302u);
}
// RNE pack -- used in epilogues / transpose
__device__ inline unsigned int pack_bf16_rne(float a, float b) {
  return (unsigned int)f2bf(a) | ((unsigned int)f2bf(b) << 16);
}
__device__ inline float fast_exp2(float x) {
#if __has_builtin(__builtin_amdgcn_exp2f)
  return __builtin_amdgcn_exp2f(x);
#else
  return exp2f(x);
#endif
}

// ---------------------------------------------------------------------------
// Fold BN into conv weights: W'[o][c] = W[o][c]*inv_o (bf16), bias_o.
// ---------------------------------------------------------------------------
__global__ __launch_bounds__(256) void fold_weights(
    const float* __restrict__ qkv_w, const float* __restrict__ qg,
    const float* __restrict__ qb, const float* __restrict__ qm,
    const float* __restrict__ qv,
    const float* __restrict__ proj_w, const float* __restrict__ pg,
    const float* __restrict__ pb, const float* __restrict__ pm,
    const float* __restrict__ pv,
    unsigned short* __restrict__ wq, float* __restrict__ biasq,
    unsigned short* __restrict__ wp, float* __restrict__ biasp)
{
  const int o = blockIdx.x, c = threadIdx.x;
  if (o < QKV_OUT_) {
    float inv = qg[o] * rsqrtf(qv[o] + BN_EPS);
    wq[o * C_ + c] = f2bf(qkv_w[o * C_ + c] * inv);
    if (c == 0) biasq[o] = qb[o] - qm[o] * inv;
  } else {
    int oo = o - QKV_OUT_;
    float inv = pg[oo] * rsqrtf(pv[oo] + BN_EPS);
    wp[oo * C_ + c] = f2bf(proj_w[oo * C_ + c] * inv);
    if (c == 0) biasp[oo] = pb[oo] - pm[oo] * inv;
  }
}

// ---------------------------------------------------------------------------
// Transpose x: planar f32 [b][c][n] -> token-major bf16 xT[b][n][c].
// Block: 64c x 64n tile through LDS [64][69] (69: conflict-free col reads).
// ---------------------------------------------------------------------------
__global__ __launch_bounds__(256) void transpose_x(
    const float* __restrict__ x, unsigned short* __restrict__ xT)
{
  __shared__ float t[64][69];
  const int tid = threadIdx.x;
  const int nt = blockIdx.x, ct = blockIdx.y, b = blockIdx.z;
  const int n0 = nt * 64, c0 = ct * 64;

  #pragma unroll
  for (int it = 0; it < 4; ++it) {
    int cl = it * 16 + (tid >> 4);
    int nl = (tid & 15) * 4;
    float4 v = *(const float4*)(x + ((size_t)b * C_ + c0 + cl) * N_ + n0 + nl);
    t[cl][nl + 0] = v.x; t[cl][nl + 1] = v.y;
    t[cl][nl + 2] = v.z; t[cl][nl + 3] = v.w;
  }
  __syncthreads();

  const int nr = tid >> 2, cseg = (tid & 3) * 16;
  unsigned int pk[8];
  #pragma unroll
  for (int q = 0; q < 8; ++q)
    pk[q] = pack_bf16_rne(t[cseg + 2 * q][nr], t[cseg + 2 * q + 1][nr]);
  unsigned short* row = xT + ((size_t)b * N_ + n0 + nr) * C_ + c0 + cseg;
  *(uint4*)(row)     = make_uint4(pk[0], pk[1], pk[2], pk[3]);
  *(uint4*)(row + 8) = make_uint4(pk[4], pk[5], pk[6], pk[7]);
}

// ---------------------------------------------------------------------------
// Direct-fragment MFMA GEMM + bias: out[o][n] = sum_c W'[o][c] inT[n][c] + b_o
// No LDS, no barriers: A (W-row) and B (token-row) fragments are 16B global
// loads.  Block = 4 waves; wave = 32o x (NSUB*32)n.
// MODE 0 (qkv, NSUB=4): wm=0 -> qkT[b][h][token][32] (q cc0..15, k 16..31);
//                       wm=1 -> planar bf16 vbuf[b][cv][n].
// MODE 1 (proj, NSUB=2): planar f32 out.
// ---------------------------------------------------------------------------
template <int MODE, int NSUB>
__global__ __launch_bounds__(256) void gemm_direct(
    const unsigned short* __restrict__ inT, const unsigned short* __restrict__ wfold,
    const float* __restrict__ bias,
    unsigned short* __restrict__ qkT, unsigned short* __restrict__ vbuf,
    float* __restrict__ outf)
{
  const int tid = threadIdx.x;
  const int wave = tid >> 6, lane = tid & 63, l31 = lane & 31, lh = lane >> 5;
  const int wm = wave & 1, wn = wave >> 1;
  const int nt = blockIdx.x, ot = blockIdx.y, b = blockIdx.z;
  const int nbase = nt * (NSUB * 64) + wn * (NSUB * 32);

  const unsigned short* wrow = wfold + (size_t)(ot * 64 + wm * 32 + l31) * C_ + lh * 8;
  const unsigned short* brow[NSUB];
  #pragma unroll
  for (int sub = 0; sub < NSUB; ++sub)
    brow[sub] = inT + ((size_t)b * N_ + nbase + sub * 32 + l31) * C_ + lh * 8;

  float16 acc[NSUB];
  #pragma unroll
  for (int i = 0; i < NSUB; ++i) acc[i] = zero16();

  #pragma unroll
  for (int s = 0; s < 16; ++s) {
    short8 a8 = *(const short8*)(wrow + s * 16);
    #pragma unroll
    for (int sub = 0; sub < NSUB; ++sub) {
      short8 b8 = *(const short8*)(brow[sub] + s * 16);
      acc[sub] = __builtin_amdgcn_mfma_f32_32x32x16_bf16(a8, b8, acc[sub], 0, 0, 0);
    }
  }

  if constexpr (MODE == 0) {
    if (wm == 0) {
      // q+k -> token-major qkT[b][h=ot][token][cc]
      #pragma unroll
      for (int sub = 0; sub < NSUB; ++sub) {
        int token = nbase + sub * 32 + l31;
        unsigned short* row = qkT + (((size_t)b * NH + ot) * N_ + token) * 32;
        #pragma unroll
        for (int qd = 0; qd < 4; ++qd) {
          int cc0 = 8 * qd + 4 * lh;
          ushort4 r;
          r.x = f2bf(acc[sub][4 * qd + 0] + bias[ot * 64 + cc0 + 0]);
          r.y = f2bf(acc[sub][4 * qd + 1] + bias[ot * 64 + cc0 + 1]);
          r.z = f2bf(acc[sub][4 * qd + 2] + bias[ot * 64 + cc0 + 2]);
          r.w = f2bf(acc[sub][4 * qd + 3] + bias[ot * 64 + cc0 + 3]);
          *(ushort4*)(row + cc0) = r;
        }
      }
    } else {
      // v -> planar bf16 vbuf[b][ot*32+cc][n]
      #pragma unroll
      for (int r = 0; r < 16; ++r) {
        int cc = (r & 3) + 8 * (r >> 2) + 4 * lh;
        float bo = bias[ot * 64 + 32 + cc];
        unsigned short* vrow = vbuf + ((size_t)b * C_ + ot * 32 + cc) * N_ + nbase + l31;
        #pragma unroll
        for (int sub = 0; sub < NSUB; ++sub)
          vrow[sub * 32] = f2bf(acc[sub][r] + bo);
      }
    }
  } else {
    #pragma unroll
    for (int r = 0; r < 16; ++r) {
      int o = ot * 64 + wm * 32 + (r & 3) + 8 * (r >> 2) + 4 * lh;
      float bo = bias[o];
      float* orow = outf + ((size_t)b * C_ + o) * N_ + nbase + l31;
      #pragma unroll
      for (int sub = 0; sub < NSUB; ++sub)
        orow[sub * 32] = acc[sub][r] + bo;
    }
  }
}

// ---------------------------------------------------------------------------
// depthwise 3x3 + BN on v (bf16 planar) -> posenc f32 planar (no add).
// ---------------------------------------------------------------------------
__global__ __launch_bounds__(256) void dwconv_bn(
    const unsigned short* __restrict__ vbuf, const float* __restrict__ pw,
    const float* __restrict__ gamma, const float* __restrict__ beta,
    const float* __restrict__ mean, const float* __restrict__ var,
    float* __restrict__ posenc)
{
  __shared__ float t[34][34];
  const int c = blockIdx.x, b = blockIdx.y;
  const int tid = threadIdx.x;
  const unsigned short* vp = vbuf + ((size_t)b * C_ + c) * N_;

  #pragma unroll
  for (int r = 0; r < 4; ++r) {
    int idx = r * 256 + tid;
    t[(idx >> 5) + 1][(idx & 31) + 1] = bf2f(vp[idx]);
  }
  if (tid < 34) {
    t[0][tid] = 0.f; t[33][tid] = 0.f;
    t[tid][0] = 0.f; t[tid][33] = 0.f;
  }
  __syncthreads();

  float w9[9];
  #pragma unroll
  for (int i = 0; i < 9; ++i) w9[i] = pw[c * 9 + i];
  float inv = gamma[c] * rsqrtf(var[c] + BN_EPS);
  float add = beta[c] - mean[c] * inv;

  float* op = posenc + ((size_t)b * C_ + c) * N_;
  #pragma unroll
  for (int r = 0; r < 4; ++r) {
    int idx = r * 256 + tid;
    int y = idx >> 5, x = idx & 31;
    float s = 0.f;
    #pragma unroll
    for (int dy = 0; dy < 3; ++dy)
      #pragma unroll
      for (int dx = 0; dx < 3; ++dx)
        s += t[y + dy][x + dx] * w9[dy * 3 + dx];
    op[idx] = s * inv + add;
  }
}

// ---------------------------------------------------------------------------
// Barrier-free MFMA attention + posenc add, token-major in AND out.
// One wave = 32 queries.  S^T = K (Q*scale') via mfma(A=K,B=Q); P = exp2(S^T)
// in-register transposed (perm-pack + shfl_xor(32)) into the PV B-operand.
// Epilogue: O/l + posenc, packed bf16, transposed to vattnT[b][token][c].
// ---------------------------------------------------------------------------
__global__ __launch_bounds__(256) void attn_mfma(
    const unsigned short* __restrict__ qkT, const unsigned short* __restrict__ vbuf,
    const float* __restrict__ posenc, unsigned short* __restrict__ vattnT)
{
  const int wave = threadIdx.x >> 6, lane = threadIdx.x & 63;
  const int l31 = lane & 31, lh = lane >> 5;
  const int h = blockIdx.y, b = blockIdx.z;
  const int qbase = blockIdx.x * 128 + wave * 32;

  const unsigned short* qkb = qkT + ((size_t)b * NH + h) * N_ * 32;
  const unsigned short* vp = vbuf + ((size_t)b * C_ + h * HD + l31) * N_;

  // Q fragment (B of S^T): B[k=d][n=query=l31]; fold scale*log2e
  short8 qf;
  {
    const unsigned short* qr = qkb + (size_t)(qbase + l31) * 32 + lh * 8;
    #pragma unroll
    for (int j = 0; j < 8; ++j)
      qf[j] = (short)f2bf(bf2f(qr[j]) * SCALE2_);
  }

  float16 oacc = zero16();
  float ls[8];
  #pragma unroll
  for (int q = 0; q < 8; ++q) ls[q] = 0.f;

  for (int kc = 0; kc < N_; kc += 128) {
    #pragma unroll
    for (int t = 0; t < 4; ++t) {
      int key0 = kc + t * 32;
      short8 kf = *(const short8*)(qkb + (size_t)(key0 + l31) * 32 + 16 + lh * 8);
      float16 st = __builtin_amdgcn_mfma_f32_32x32x16_bf16(kf, qf, zero16(), 0, 0, 0);

      unsigned int u[8];
      #pragma unroll
      for (int q = 0; q < 8; ++q) {
        float pe = fast_exp2(st[2 * q]);
        float po = fast_exp2(st[2 * q + 1]);
        ls[q] += pe + po;           // 8 independent accumulation chains
        u[q] = pack_bf16_trunc(pe, po);
      }
      unsigned int e[8];
      #pragma unroll
      for (int q = 0; q < 8; ++q)
        e[q] = (unsigned int)__shfl_xor((int)u[q], 32, 64);

      #pragma unroll
      for (int f = 0; f < 2; ++f) {
        union { unsigned int w[4]; short8 s; } bf;
        int q0 = f * 4;
        bf.w[0] = lh ? e[q0 + 2] : u[q0 + 0];
        bf.w[1] = lh ? e[q0 + 3] : u[q0 + 1];
        bf.w[2] = lh ? u[q0 + 2] : e[q0 + 0];
        bf.w[3] = lh ? u[q0 + 3] : e[q0 + 1];
        short8 vf = *(const short8*)(vp + key0 + f * 16 + lh * 8);
        oacc = __builtin_amdgcn_mfma_f32_32x32x16_bf16(vf, bf.s, oacc, 0, 0, 0);
      }
    }
  }

  float lsum = ((ls[0] + ls[1]) + (ls[2] + ls[3])) + ((ls[4] + ls[5]) + (ls[6] + ls[7]));
  lsum += __shfl_xor(lsum, 32, 64);
  float linv = 1.f / lsum;

  // epilogue: val = O/l + posenc; transpose to token-major bf16
  const int token = qbase + l31;
  float val[16];
  #pragma unroll
  for (int r = 0; r < 16; ++r) {
    int d = (r & 3) + 8 * (r >> 2) + 4 * lh;
    val[r] = oacc[r] * linv + posenc[((size_t)b * C_ + h * HD + d) * N_ + token];
  }
  unsigned int u[8];
  #pragma unroll
  for (int m = 0; m < 8; ++m) u[m] = pack_bf16_rne(val[2 * m], val[2 * m + 1]);
  unsigned int e[8];
  #pragma unroll
  for (int m = 0; m < 8; ++m) e[m] = (unsigned int)__shfl_xor((int)u[m], 32, 64);

  unsigned short* row = vattnT + ((size_t)b * N_ + token) * C_ + h * HD + lh * 16;
  uint4 w0, w1;
  if (lh == 0) {
    w0 = make_uint4(u[0], u[1], e[0], e[1]);
    w1 = make_uint4(u[2], u[3], e[2], e[3]);
  } else {
    w0 = make_uint4(e[4], e[5], u[4], u[5]);
    w1 = make_uint4(e[6], e[7], u[6], u[7]);
  }
  *(uint4*)(row)     = w0;
  *(uint4*)(row + 8) = w1;
}

// ---------------------------------------------------------------------------
extern "C" void kernel_launch(void* const* d_in, const int* in_sizes, int n_in,
                              void* d_out, int out_size, void* d_ws, size_t ws_size,
                              hipStream_t stream) {
  const float* x          = (const float*)d_in[0];
  const float* qkv_w      = (const float*)d_in[1];
  const float* qkv_gamma  = (const float*)d_in[2];
  const float* qkv_beta   = (const float*)d_in[3];
  const float* qkv_mean   = (const float*)d_in[4];
  const float* qkv_var    = (const float*)d_in[5];
  const float* pe_w       = (const float*)d_in[6];
  const float* pe_gamma   = (const float*)d_in[7];
  const float* pe_beta    = (const float*)d_in[8];
  const float* pe_mean    = (const float*)d_in[9];
  const float* pe_var     = (const float*)d_in[10];
  const float* proj_w     = (const float*)d_in[11];
  const float* proj_gamma = (const float*)d_in[12];
  const float* proj_beta  = (const float*)d_in[13];
  const float* proj_mean  = (const float*)d_in[14];
  const float* proj_var   = (const float*)d_in[15];
  float* out = (float*)d_out;

  char* ws = (char*)d_ws;
  unsigned short* qkT = (unsigned short*)ws;                      // 8 MB
  ws += (size_t)B_ * NH * N_ * 32 * sizeof(unsigned short);
  unsigned short* vbuf = (unsigned short*)ws;                     // 8 MB
  ws += (size_t)B_ * C_ * N_ * sizeof(unsigned short);
  unsigned short* xT = (unsigned short*)ws;                       // 8 MB
  ws += (size_t)B_ * N_ * C_ * sizeof(unsigned short);
  unsigned short* vattnT = (unsigned short*)ws;                   // 8 MB
  ws += (size_t)B_ * N_ * C_ * sizeof(unsigned short);
  float* posenc = (float*)ws;                                     // 16 MB
  ws += (size_t)B_ * C_ * N_ * sizeof(float);
  unsigned short* wq = (unsigned short*)ws;
  ws += (size_t)QKV_OUT_ * C_ * sizeof(unsigned short);
  unsigned short* wp = (unsigned short*)ws;
  ws += (size_t)C_ * C_ * sizeof(unsigned short);
  float* biasq = (float*)ws; ws += QKV_OUT_ * sizeof(float);
  float* biasp = (float*)ws;

  // 0a) fold BN into weights
  fold_weights<<<dim3(QKV_OUT_ + C_), 256, 0, stream>>>(
      qkv_w, qkv_gamma, qkv_beta, qkv_mean, qkv_var,
      proj_w, proj_gamma, proj_beta, proj_mean, proj_var,
      wq, biasq, wp, biasp);
  // 0b) x -> token-major bf16
  transpose_x<<<dim3(16, 4, 16), 256, 0, stream>>>(x, xT);

  // 1) qkv GEMM (direct fragments) -> qkT + vbuf
  gemm_direct<0, 4><<<dim3(4, 8, 16), 256, 0, stream>>>(
      xT, wq, biasq, qkT, vbuf, nullptr);

  // 2) posenc = BN(dwconv3x3(v))
  dwconv_bn<<<dim3(C_, B_), 256, 0, stream>>>(
      vbuf, pe_w, pe_gamma, pe_beta, pe_mean, pe_var, posenc);

  // 3) attention + posenc add -> vattnT (token-major bf16)
  attn_mfma<<<dim3(8, NH, B_), 256, 0, stream>>>(qkT, vbuf, posenc, vattnT);

  // 4) proj GEMM (direct fragments) -> out f32
  gemm_direct<1, 2><<<dim3(8, 4, 16), 256, 0, stream>>>(
      vattnT, wp, biasp, nullptr, nullptr, out);
}

// Round 6
// 177.323 us; speedup vs baseline: 1.1044x; 1.1044x over previous
//
#include <hip/hip_runtime.h>

#define B_ 16
#define C_ 256
#define N_ 1024
#define NH 8
#define HD 32
#define KD 16
#define QKV_OUT_ 512
#define BN_EPS 1e-3f
// scale folded with 1/ln2 so softmax uses native exp2
#define SCALE2_ (0.25f * 1.44269504088896f)

typedef __attribute__((ext_vector_type(8))) short short8;
typedef __attribute__((ext_vector_type(16))) float float16;

__device__ inline unsigned short f2bf(float f) {
  unsigned int u = __float_as_uint(f);
  return (unsigned short)((u + 0x7FFF + ((u >> 16) & 1)) >> 16);  // RNE
}
__device__ inline float bf2f(unsigned short s) {
  return __uint_as_float(((unsigned int)s) << 16);
}
__device__ inline float16 zero16() {
  float16 z;
  #pragma unroll
  for (int i = 0; i < 16; ++i) z[i] = 0.f;
  return z;
}
__device__ inline unsigned int pack_bf16_trunc(float a, float b) {
  return __builtin_amdgcn_perm(__float_as_uint(b), __float_as_uint(a), 0x07060302u);
}
__device__ inline unsigned int pack_bf16_rne(float a, float b) {
  return (unsigned int)f2bf(a) | ((unsigned int)f2bf(b) << 16);
}
__device__ inline float fast_exp2(float x) {
#if __has_builtin(__builtin_amdgcn_exp2f)
  return __builtin_amdgcn_exp2f(x);
#else
  return exp2f(x);
#endif
}

// ---------------------------------------------------------------------------
// Fold BN into conv weights: W'[o][c] = W[o][c]*inv_o (bf16), bias_o.
// ---------------------------------------------------------------------------
__global__ __launch_bounds__(256) void fold_weights(
    const float* __restrict__ qkv_w, const float* __restrict__ qg,
    const float* __restrict__ qb, const float* __restrict__ qm,
    const float* __restrict__ qv,
    const float* __restrict__ proj_w, const float* __restrict__ pg,
    const float* __restrict__ pb, const float* __restrict__ pm,
    const float* __restrict__ pv,
    unsigned short* __restrict__ wq, float* __restrict__ biasq,
    unsigned short* __restrict__ wp, float* __restrict__ biasp)
{
  const int o = blockIdx.x, c = threadIdx.x;
  if (o < QKV_OUT_) {
    float inv = qg[o] * rsqrtf(qv[o] + BN_EPS);
    wq[o * C_ + c] = f2bf(qkv_w[o * C_ + c] * inv);
    if (c == 0) biasq[o] = qb[o] - qm[o] * inv;
  } else {
    int oo = o - QKV_OUT_;
    float inv = pg[oo] * rsqrtf(pv[oo] + BN_EPS);
    wp[oo * C_ + c] = f2bf(proj_w[oo * C_ + c] * inv);
    if (c == 0) biasp[oo] = pb[oo] - pm[oo] * inv;
  }
}

// ---------------------------------------------------------------------------
// Transpose x: planar f32 [b][c][n] -> token-major bf16 xT[b][n][c].
// ---------------------------------------------------------------------------
__global__ __launch_bounds__(256) void transpose_x(
    const float* __restrict__ x, unsigned short* __restrict__ xT)
{
  __shared__ float t[64][69];
  const int tid = threadIdx.x;
  const int nt = blockIdx.x, ct = blockIdx.y, b = blockIdx.z;
  const int n0 = nt * 64, c0 = ct * 64;

  #pragma unroll
  for (int it = 0; it < 4; ++it) {
    int cl = it * 16 + (tid >> 4);
    int nl = (tid & 15) * 4;
    float4 v = *(const float4*)(x + ((size_t)b * C_ + c0 + cl) * N_ + n0 + nl);
    t[cl][nl + 0] = v.x; t[cl][nl + 1] = v.y;
    t[cl][nl + 2] = v.z; t[cl][nl + 3] = v.w;
  }
  __syncthreads();

  const int nr = tid >> 2, cseg = (tid & 3) * 16;
  unsigned int pk[8];
  #pragma unroll
  for (int q = 0; q < 8; ++q)
    pk[q] = pack_bf16_rne(t[cseg + 2 * q][nr], t[cseg + 2 * q + 1][nr]);
  unsigned short* row = xT + ((size_t)b * N_ + n0 + nr) * C_ + c0 + cseg;
  *(uint4*)(row)     = make_uint4(pk[0], pk[1], pk[2], pk[3]);
  *(uint4*)(row + 8) = make_uint4(pk[4], pk[5], pk[6], pk[7]);
}

// ---------------------------------------------------------------------------
// Tiled MFMA GEMM (m97-style): out[o][tok] = sum_c W'[o][c] inT[tok][c] + b_o
// M x N x K = (512|256) x 16384 x 256.  Block: 256 thr = 2x2 waves, tile
// 128(o) x 128(tok), BK=64 staged in LDS (72-short padded rows, conflict-free
// b128 reads).  Wave: 2x2 fragments of 32x32.  2 barriers per K-chunk.
// MODE 0 (qkv): am=0 frag -> qkT[b][h][token][32] (q cc0..15,k 16..31);
//               am=1 frag -> planar bf16 vbuf[b][h*32+d][n].
// MODE 1 (proj): planar f32 out.
// ---------------------------------------------------------------------------
template <int MODE>
__global__ __launch_bounds__(256) void gemm_tiled(
    const unsigned short* __restrict__ inT, const unsigned short* __restrict__ wfold,
    const float* __restrict__ bias,
    unsigned short* __restrict__ qkT, unsigned short* __restrict__ vbuf,
    float* __restrict__ outf)
{
  __shared__ __align__(16) unsigned short wa[128 * 72];
  __shared__ __align__(16) unsigned short xb[128 * 72];
  const int tid = threadIdx.x;
  const int wave = tid >> 6, lane = tid & 63, l31 = lane & 31, lh = lane >> 5;
  const int wm = wave & 1, wn = wave >> 1;
  const int n0g = blockIdx.x * 128;        // global token base
  const int o0 = blockIdx.y * 128;
  const int b = n0g >> 10, nloc = n0g & 1023;

  const int sr = tid >> 3, sseg = (tid & 7) * 8;  // staging: 32 rows/round

  float16 acc[2][2];
  #pragma unroll
  for (int i = 0; i < 2; ++i)
    #pragma unroll
    for (int j = 0; j < 2; ++j) acc[i][j] = zero16();

  for (int kc = 0; kc < 4; ++kc) {
    __syncthreads();
    #pragma unroll
    for (int rr = 0; rr < 4; ++rr) {
      int r = rr * 32 + sr;
      *(uint4*)&wa[r * 72 + sseg] =
          *(const uint4*)(wfold + (size_t)(o0 + r) * C_ + kc * 64 + sseg);
      *(uint4*)&xb[r * 72 + sseg] =
          *(const uint4*)(inT + (size_t)(n0g + r) * C_ + kc * 64 + sseg);
    }
    __syncthreads();

    #pragma unroll
    for (int ks = 0; ks < 4; ++ks) {
      const int ko = ks * 16 + lh * 8;
      short8 a0 = *(const short8*)&wa[(wm * 64 + l31) * 72 + ko];
      short8 a1 = *(const short8*)&wa[(wm * 64 + 32 + l31) * 72 + ko];
      short8 b0 = *(const short8*)&xb[(wn * 64 + l31) * 72 + ko];
      short8 b1 = *(const short8*)&xb[(wn * 64 + 32 + l31) * 72 + ko];
      acc[0][0] = __builtin_amdgcn_mfma_f32_32x32x16_bf16(a0, b0, acc[0][0], 0, 0, 0);
      acc[0][1] = __builtin_amdgcn_mfma_f32_32x32x16_bf16(a0, b1, acc[0][1], 0, 0, 0);
      acc[1][0] = __builtin_amdgcn_mfma_f32_32x32x16_bf16(a1, b0, acc[1][0], 0, 0, 0);
      acc[1][1] = __builtin_amdgcn_mfma_f32_32x32x16_bf16(a1, b1, acc[1][1], 0, 0, 0);
    }
  }

  if constexpr (MODE == 0) {
    const int h = (o0 >> 6) + wm * 2 /* o0/64 + wm*... */;
    // NOTE: o0 is multiple of 128 -> o0/64 even; head of am=0/1 = o0/64 + wm? No:
    // o = o0 + wm*64 + am*32 + row; h = o>>6 = (o0>>6) + wm (am*32+row < 64).
    const int hh = (o0 >> 6) + wm;
    (void)h;
    // ---- am=0: q+k -> token-major qkT
    #pragma unroll
    for (int bn = 0; bn < 2; ++bn) {
      int n = nloc + wn * 64 + bn * 32 + l31;
      unsigned short* row = qkT + (((size_t)b * NH + hh) * N_ + n) * 32;
      #pragma unroll
      for (int qd = 0; qd < 4; ++qd) {
        int cc0 = 8 * qd + 4 * lh;
        ushort4 rv;
        rv.x = f2bf(acc[0][bn][4 * qd + 0] + bias[hh * 64 + cc0 + 0]);
        rv.y = f2bf(acc[0][bn][4 * qd + 1] + bias[hh * 64 + cc0 + 1]);
        rv.z = f2bf(acc[0][bn][4 * qd + 2] + bias[hh * 64 + cc0 + 2]);
        rv.w = f2bf(acc[0][bn][4 * qd + 3] + bias[hh * 64 + cc0 + 3]);
        *(ushort4*)(row + cc0) = rv;
      }
    }
    // ---- am=1: v -> planar bf16 vbuf
    #pragma unroll
    for (int r = 0; r < 16; ++r) {
      int d = (r & 3) + 8 * (r >> 2) + 4 * lh;
      float bo = bias[hh * 64 + 32 + d];
      unsigned short* vrow =
          vbuf + ((size_t)b * C_ + hh * 32 + d) * N_ + nloc + wn * 64 + l31;
      #pragma unroll
      for (int bn = 0; bn < 2; ++bn)
        vrow[bn * 32] = f2bf(acc[1][bn][r] + bo);
    }
  } else {
    #pragma unroll
    for (int am = 0; am < 2; ++am) {
      #pragma unroll
      for (int r = 0; r < 16; ++r) {
        int o = o0 + wm * 64 + am * 32 + (r & 3) + 8 * (r >> 2) + 4 * lh;
        float bo = bias[o];
        float* orow = outf + ((size_t)b * C_ + o) * N_ + nloc + wn * 64 + l31;
        #pragma unroll
        for (int bn = 0; bn < 2; ++bn)
          orow[bn * 32] = acc[am][bn][r] + bo;
      }
    }
  }
}

// ---------------------------------------------------------------------------
// depthwise 3x3 + BN on v (bf16 planar) -> posenc f32 planar.
// ---------------------------------------------------------------------------
__global__ __launch_bounds__(256) void dwconv_bn(
    const unsigned short* __restrict__ vbuf, const float* __restrict__ pw,
    const float* __restrict__ gamma, const float* __restrict__ beta,
    const float* __restrict__ mean, const float* __restrict__ var,
    float* __restrict__ posenc)
{
  __shared__ float t[34][34];
  const int c = blockIdx.x, b = blockIdx.y;
  const int tid = threadIdx.x;
  const unsigned short* vp = vbuf + ((size_t)b * C_ + c) * N_;

  #pragma unroll
  for (int r = 0; r < 4; ++r) {
    int idx = r * 256 + tid;
    t[(idx >> 5) + 1][(idx & 31) + 1] = bf2f(vp[idx]);
  }
  if (tid < 34) {
    t[0][tid] = 0.f; t[33][tid] = 0.f;
    t[tid][0] = 0.f; t[tid][33] = 0.f;
  }
  __syncthreads();

  float w9[9];
  #pragma unroll
  for (int i = 0; i < 9; ++i) w9[i] = pw[c * 9 + i];
  float inv = gamma[c] * rsqrtf(var[c] + BN_EPS);
  float add = beta[c] - mean[c] * inv;

  float* op = posenc + ((size_t)b * C_ + c) * N_;
  #pragma unroll
  for (int r = 0; r < 4; ++r) {
    int idx = r * 256 + tid;
    int y = idx >> 5, x = idx & 31;
    float s = 0.f;
    #pragma unroll
    for (int dy = 0; dy < 3; ++dy)
      #pragma unroll
      for (int dx = 0; dx < 3; ++dx)
        s += t[y + dy][x + dx] * w9[dy * 3 + dx];
    op[idx] = s * inv + add;
  }
}

// ---------------------------------------------------------------------------
// MFMA attention with block-cooperative LDS K/V staging (double-buffered,
// one barrier per 128-key chunk).  4 waves x 32 queries, same (b,h).
// S^T = K(Q*scale') via mfma(A=K,B=Q); P in-register (perm-pack+shfl_xor32)
// into PV B-operand.  Epilogue adds posenc, writes token-major bf16.
// ---------------------------------------------------------------------------
__global__ __launch_bounds__(256) void attn_mfma(
    const unsigned short* __restrict__ qkT, const unsigned short* __restrict__ vbuf,
    const float* __restrict__ posenc, unsigned short* __restrict__ vattnT)
{
  __shared__ __align__(16) unsigned short k_lds[2][128 * 24];  // [key][d] 48B rows
  __shared__ __align__(16) unsigned short v_lds[2][32 * 136];  // [d][key] 272B rows

  const int tid = threadIdx.x;
  const int wave = tid >> 6, lane = tid & 63;
  const int l31 = lane & 31, lh = lane >> 5;
  const int h = blockIdx.y, b = blockIdx.z;
  const int qbase = blockIdx.x * 128 + wave * 32;

  const unsigned short* qkb = qkT + ((size_t)b * NH + h) * N_ * 32;
  const unsigned short* vhead = vbuf + ((size_t)b * C_ + h * HD) * N_;

  // staging indices
  const int skey = tid >> 1, shalf = tid & 1;          // K: 128 keys x 2 halves
  const int svd = tid >> 4, svseg = tid & 15;          // V: 16 d x 16 segs /round

  // Q fragment (B of S^T): B[k=d][n=query=l31]; fold scale*log2e
  short8 qf;
  {
    const unsigned short* qr = qkb + (size_t)(qbase + l31) * 32 + lh * 8;
    #pragma unroll
    for (int j = 0; j < 8; ++j)
      qf[j] = (short)f2bf(bf2f(qr[j]) * SCALE2_);
  }

  // prologue: stage chunk 0 into buf 0
  {
    *(uint4*)&k_lds[0][skey * 24 + shalf * 8] =
        *(const uint4*)(qkb + (size_t)skey * 32 + 16 + shalf * 8);
    #pragma unroll
    for (int r = 0; r < 2; ++r) {
      int d = r * 16 + svd;
      *(uint4*)&v_lds[0][d * 136 + svseg * 8] =
          *(const uint4*)(vhead + (size_t)d * N_ + svseg * 8);
    }
  }
  __syncthreads();

  float16 oacc = zero16();
  float ls[8];
  #pragma unroll
  for (int q = 0; q < 8; ++q) ls[q] = 0.f;

  for (int c = 0; c < 8; ++c) {
    const int buf = c & 1;
    // stage next chunk into buf^1 (global loads issue early, overlap compute)
    if (c < 7) {
      int kc = (c + 1) * 128;
      *(uint4*)&k_lds[buf ^ 1][skey * 24 + shalf * 8] =
          *(const uint4*)(qkb + (size_t)(kc + skey) * 32 + 16 + shalf * 8);
      #pragma unroll
      for (int r = 0; r < 2; ++r) {
        int d = r * 16 + svd;
        *(uint4*)&v_lds[buf ^ 1][d * 136 + svseg * 8] =
            *(const uint4*)(vhead + (size_t)d * N_ + kc + svseg * 8);
      }
    }

    #pragma unroll
    for (int t = 0; t < 4; ++t) {
      const int key0 = t * 32;
      short8 kf = *(const short8*)&k_lds[buf][(key0 + l31) * 24 + lh * 8];
      float16 st = __builtin_amdgcn_mfma_f32_32x32x16_bf16(kf, qf, zero16(), 0, 0, 0);

      unsigned int u[8];
      #pragma unroll
      for (int q = 0; q < 8; ++q) {
        float pe = fast_exp2(st[2 * q]);
        float po = fast_exp2(st[2 * q + 1]);
        ls[q] += pe + po;
        u[q] = pack_bf16_trunc(pe, po);
      }
      unsigned int e[8];
      #pragma unroll
      for (int q = 0; q < 8; ++q)
        e[q] = (unsigned int)__shfl_xor((int)u[q], 32, 64);

      #pragma unroll
      for (int f = 0; f < 2; ++f) {
        union { unsigned int w[4]; short8 s; } bf;
        int q0 = f * 4;
        bf.w[0] = lh ? e[q0 + 2] : u[q0 + 0];
        bf.w[1] = lh ? e[q0 + 3] : u[q0 + 1];
        bf.w[2] = lh ? u[q0 + 2] : e[q0 + 0];
        bf.w[3] = lh ? u[q0 + 3] : e[q0 + 1];
        short8 vf = *(const short8*)&v_lds[buf][l31 * 136 + key0 + f * 16 + lh * 8];
        oacc = __builtin_amdgcn_mfma_f32_32x32x16_bf16(vf, bf.s, oacc, 0, 0, 0);
      }
    }
    __syncthreads();  // staging of buf^1 complete; reads of buf done
  }

  float lsum = ((ls[0] + ls[1]) + (ls[2] + ls[3])) + ((ls[4] + ls[5]) + (ls[6] + ls[7]));
  lsum += __shfl_xor(lsum, 32, 64);
  float linv = 1.f / lsum;

  // epilogue: val = O/l + posenc; transpose to token-major bf16
  const int token = qbase + l31;
  float val[16];
  #pragma unroll
  for (int r = 0; r < 16; ++r) {
    int d = (r & 3) + 8 * (r >> 2) + 4 * lh;
    val[r] = oacc[r] * linv + posenc[((size_t)b * C_ + h * HD + d) * N_ + token];
  }
  unsigned int u[8];
  #pragma unroll
  for (int m = 0; m < 8; ++m) u[m] = pack_bf16_rne(val[2 * m], val[2 * m + 1]);
  unsigned int e[8];
  #pragma unroll
  for (int m = 0; m < 8; ++m) e[m] = (unsigned int)__shfl_xor((int)u[m], 32, 64);

  unsigned short* row = vattnT + ((size_t)b * N_ + token) * C_ + h * HD + lh * 16;
  uint4 w0, w1;
  if (lh == 0) {
    w0 = make_uint4(u[0], u[1], e[0], e[1]);
    w1 = make_uint4(u[2], u[3], e[2], e[3]);
  } else {
    w0 = make_uint4(e[4], e[5], u[4], u[5]);
    w1 = make_uint4(e[6], e[7], u[6], u[7]);
  }
  *(uint4*)(row)     = w0;
  *(uint4*)(row + 8) = w1;
}

// ---------------------------------------------------------------------------
extern "C" void kernel_launch(void* const* d_in, const int* in_sizes, int n_in,
                              void* d_out, int out_size, void* d_ws, size_t ws_size,
                              hipStream_t stream) {
  const float* x          = (const float*)d_in[0];
  const float* qkv_w      = (const float*)d_in[1];
  const float* qkv_gamma  = (const float*)d_in[2];
  const float* qkv_beta   = (const float*)d_in[3];
  const float* qkv_mean   = (const float*)d_in[4];
  const float* qkv_var    = (const float*)d_in[5];
  const float* pe_w       = (const float*)d_in[6];
  const float* pe_gamma   = (const float*)d_in[7];
  const float* pe_beta    = (const float*)d_in[8];
  const float* pe_mean    = (const float*)d_in[9];
  const float* pe_var     = (const float*)d_in[10];
  const float* proj_w     = (const float*)d_in[11];
  const float* proj_gamma = (const float*)d_in[12];
  const float* proj_beta  = (const float*)d_in[13];
  const float* proj_mean  = (const float*)d_in[14];
  const float* proj_var   = (const float*)d_in[15];
  float* out = (float*)d_out;

  char* ws = (char*)d_ws;
  unsigned short* qkT = (unsigned short*)ws;                      // 8 MB
  ws += (size_t)B_ * NH * N_ * 32 * sizeof(unsigned short);
  unsigned short* vbuf = (unsigned short*)ws;                     // 8 MB
  ws += (size_t)B_ * C_ * N_ * sizeof(unsigned short);
  unsigned short* xT = (unsigned short*)ws;                       // 8 MB
  ws += (size_t)B_ * N_ * C_ * sizeof(unsigned short);
  unsigned short* vattnT = (unsigned short*)ws;                   // 8 MB
  ws += (size_t)B_ * N_ * C_ * sizeof(unsigned short);
  float* posenc = (float*)ws;                                     // 16 MB
  ws += (size_t)B_ * C_ * N_ * sizeof(float);
  unsigned short* wq = (unsigned short*)ws;
  ws += (size_t)QKV_OUT_ * C_ * sizeof(unsigned short);
  unsigned short* wp = (unsigned short*)ws;
  ws += (size_t)C_ * C_ * sizeof(unsigned short);
  float* biasq = (float*)ws; ws += QKV_OUT_ * sizeof(float);
  float* biasp = (float*)ws;

  // 0a) fold BN into weights; 0b) x -> token-major bf16
  fold_weights<<<dim3(QKV_OUT_ + C_), 256, 0, stream>>>(
      qkv_w, qkv_gamma, qkv_beta, qkv_mean, qkv_var,
      proj_w, proj_gamma, proj_beta, proj_mean, proj_var,
      wq, biasq, wp, biasp);
  transpose_x<<<dim3(16, 4, 16), 256, 0, stream>>>(x, xT);

  // 1) qkv GEMM (tiled) -> qkT + vbuf
  gemm_tiled<0><<<dim3(128, 4), 256, 0, stream>>>(
      xT, wq, biasq, qkT, vbuf, nullptr);

  // 2) posenc = BN(dwconv3x3(v))
  dwconv_bn<<<dim3(C_, B_), 256, 0, stream>>>(
      vbuf, pe_w, pe_gamma, pe_beta, pe_mean, pe_var, posenc);

  // 3) attention + posenc -> vattnT (token-major bf16)
  attn_mfma<<<dim3(8, NH, B_), 256, 0, stream>>>(qkT, vbuf, posenc, vattnT);

  // 4) proj GEMM (tiled) -> out f32
  gemm_tiled<1><<<dim3(128, 2), 256, 0, stream>>>(
      vattnT, wp, biasp, nullptr, nullptr, out);
}

// Round 7
// 161.307 us; speedup vs baseline: 1.2141x; 1.0993x over previous
//
#include <hip/hip_runtime.h>

#define B_ 16
#define C_ 256
#define N_ 1024
#define NH 8
#define HD 32
#define KD 16
#define QKV_OUT_ 512
#define BN_EPS 1e-3f
// softmax scale * log2(e), pre-folded into the q-channel weights
#define SCALE2_ (0.25f * 1.44269504088896f)

typedef __attribute__((ext_vector_type(8))) short short8;
typedef __attribute__((ext_vector_type(16))) float float16;

__device__ inline unsigned short f2bf(float f) {
  unsigned int u = __float_as_uint(f);
  return (unsigned short)((u + 0x7FFF + ((u >> 16) & 1)) >> 16);  // RNE
}
__device__ inline float bf2f(unsigned short s) {
  return __uint_as_float(((unsigned int)s) << 16);
}
__device__ inline float16 zero16() {
  float16 z;
  #pragma unroll
  for (int i = 0; i < 16; ++i) z[i] = 0.f;
  return z;
}
__device__ inline unsigned int pack_bf16_trunc(float a, float b) {
  return __builtin_amdgcn_perm(__float_as_uint(b), __float_as_uint(a), 0x07060302u);
}
__device__ inline unsigned int pack_bf16_rne(float a, float b) {
  return (unsigned int)f2bf(a) | ((unsigned int)f2bf(b) << 16);
}
__device__ inline float fast_exp2(float x) {
#if __has_builtin(__builtin_amdgcn_exp2f)
  return __builtin_amdgcn_exp2f(x);
#else
  return exp2f(x);
#endif
}
// permlane32_swap: a' = {a.lo, b.lo}, b' = {a.hi, b.hi}
__device__ inline void pl32(unsigned int& a, unsigned int& b) {
#if __has_builtin(__builtin_amdgcn_permlane32_swap)
  typedef __attribute__((ext_vector_type(2))) int int2v;
  int2v r = __builtin_amdgcn_permlane32_swap((int)a, (int)b, false, false);
  a = (unsigned int)r[0];
  b = (unsigned int)r[1];
#else
  unsigned int ea = (unsigned int)__shfl_xor((int)a, 32, 64);
  unsigned int eb = (unsigned int)__shfl_xor((int)b, 32, 64);
  bool hi = (threadIdx.x & 32) != 0;
  unsigned int an = hi ? eb : a;
  unsigned int bn = hi ? b : ea;
  a = an; b = bn;
#endif
}
// LDS b64-pair fragment read (rows are 8B-aligned, 2-way-free strides)
__device__ inline short8 lds_frag(const unsigned short* p) {
  union { uint2 u[2]; short8 s; } r;
  r.u[0] = *(const uint2*)p;
  r.u[1] = *(const uint2*)(p + 4);
  return r.s;
}
__device__ inline void lds_store16(unsigned short* p, uint4 v) {
  *(uint2*)p = make_uint2(v.x, v.y);
  *(uint2*)(p + 4) = make_uint2(v.z, v.w);
}

// ---------------------------------------------------------------------------
// Fold BN into conv weights (bf16) + bias.  q-channels (o%64 < 16) also get
// SCALE2_ folded so attention uses raw exp2 with no Q repack.
// ---------------------------------------------------------------------------
__global__ __launch_bounds__(256) void fold_weights(
    const float* __restrict__ qkv_w, const float* __restrict__ qg,
    const float* __restrict__ qb, const float* __restrict__ qm,
    const float* __restrict__ qv,
    const float* __restrict__ proj_w, const float* __restrict__ pg,
    const float* __restrict__ pb, const float* __restrict__ pm,
    const float* __restrict__ pv,
    unsigned short* __restrict__ wq, float* __restrict__ biasq,
    unsigned short* __restrict__ wp, float* __restrict__ biasp)
{
  const int o = blockIdx.x, c = threadIdx.x;
  if (o < QKV_OUT_) {
    float s = ((o & 63) < 16) ? SCALE2_ : 1.f;
    float inv = qg[o] * rsqrtf(qv[o] + BN_EPS) * s;
    wq[o * C_ + c] = f2bf(qkv_w[o * C_ + c] * inv);
    if (c == 0) biasq[o] = qb[o] * s - qm[o] * inv;
  } else {
    int oo = o - QKV_OUT_;
    float inv = pg[oo] * rsqrtf(pv[oo] + BN_EPS);
    wp[oo * C_ + c] = f2bf(proj_w[oo * C_ + c] * inv);
    if (c == 0) biasp[oo] = pb[oo] - pm[oo] * inv;
  }
}

// ---------------------------------------------------------------------------
// Transpose x: planar f32 [b][c][n] -> token-major bf16 xT[b][n][c].
// ---------------------------------------------------------------------------
__global__ __launch_bounds__(256) void transpose_x(
    const float* __restrict__ x, unsigned short* __restrict__ xT)
{
  __shared__ float t[64][69];
  const int tid = threadIdx.x;
  const int nt = blockIdx.x, ct = blockIdx.y, b = blockIdx.z;
  const int n0 = nt * 64, c0 = ct * 64;

  #pragma unroll
  for (int it = 0; it < 4; ++it) {
    int cl = it * 16 + (tid >> 4);
    int nl = (tid & 15) * 4;
    float4 v = *(const float4*)(x + ((size_t)b * C_ + c0 + cl) * N_ + n0 + nl);
    t[cl][nl + 0] = v.x; t[cl][nl + 1] = v.y;
    t[cl][nl + 2] = v.z; t[cl][nl + 3] = v.w;
  }
  __syncthreads();

  const int nr = tid >> 2, cseg = (tid & 3) * 16;
  unsigned int pk[8];
  #pragma unroll
  for (int q = 0; q < 8; ++q)
    pk[q] = pack_bf16_rne(t[cseg + 2 * q][nr], t[cseg + 2 * q + 1][nr]);
  unsigned short* row = xT + ((size_t)b * N_ + n0 + nr) * C_ + c0 + cseg;
  *(uint4*)(row)     = make_uint4(pk[0], pk[1], pk[2], pk[3]);
  *(uint4*)(row + 8) = make_uint4(pk[4], pk[5], pk[6], pk[7]);
}

// ---------------------------------------------------------------------------
// Tiled MFMA GEMM, reg-prefetch pipeline, single barrier per K-step.
// Tile 128(o) x 128(tok), BK=32, double-buffered LDS rows of 44 shorts
// (22 dw == 2 mod 4 -> max 2-way bank aliasing = free; 8B-aligned b64 reads).
// MODE 0 (qkv): wm rows -> qkT token-major (q,k) + planar bf16 vbuf (v).
// MODE 1 (proj): planar f32 out.
// ---------------------------------------------------------------------------
template <int MODE>
__global__ __launch_bounds__(256) void gemm_tiled(
    const unsigned short* __restrict__ inT, const unsigned short* __restrict__ wfold,
    const float* __restrict__ bias,
    unsigned short* __restrict__ qkT, unsigned short* __restrict__ vbuf,
    float* __restrict__ outf)
{
  constexpr int STR = 44;
  __shared__ __align__(8) unsigned short wa[2][128 * STR];
  __shared__ __align__(8) unsigned short xb[2][128 * STR];
  const int tid = threadIdx.x;
  const int wave = tid >> 6, lane = tid & 63, l31 = lane & 31, lh = lane >> 5;
  const int wm = wave & 1, wn = wave >> 1;
  const int n0g = blockIdx.x * 128;
  const int o0 = blockIdx.y * 128;
  const int b = n0g >> 10, nloc = n0g & 1023;

  // staging map: 512 16B-slots per tile pair; thread covers slots tid, tid+256
  const int r0 = tid >> 2, oc0 = (tid & 3) * 8;          // slot tid
  const int r1 = (tid + 256) >> 2, oc1 = oc0;            // slot tid+256 (same oct)

  float16 acc[2][2];
  #pragma unroll
  for (int i = 0; i < 2; ++i)
    #pragma unroll
    for (int j = 0; j < 2; ++j) acc[i][j] = zero16();

  uint4 ga0, ga1, gb0, gb1;
  #define LOADK(kc)                                                          \
    ga0 = *(const uint4*)(wfold + (size_t)(o0 + r0) * C_ + (kc) * 32 + oc0); \
    ga1 = *(const uint4*)(wfold + (size_t)(o0 + r1) * C_ + (kc) * 32 + oc1); \
    gb0 = *(const uint4*)(inT + (size_t)(n0g + r0) * C_ + (kc) * 32 + oc0);  \
    gb1 = *(const uint4*)(inT + (size_t)(n0g + r1) * C_ + (kc) * 32 + oc1);
  #define STOREK(bufi)                                   \
    lds_store16(&wa[bufi][r0 * STR + oc0], ga0);         \
    lds_store16(&wa[bufi][r1 * STR + oc1], ga1);         \
    lds_store16(&xb[bufi][r0 * STR + oc0], gb0);         \
    lds_store16(&xb[bufi][r1 * STR + oc1], gb1);

  LOADK(0);
  STOREK(0);
  __syncthreads();

  for (int kc = 0; kc < 8; ++kc) {
    const int buf = kc & 1;
    if (kc < 7) { LOADK(kc + 1); }          // issue early, lands during MFMA

    #pragma unroll
    for (int ks = 0; ks < 2; ++ks) {
      const int ko = ks * 16 + lh * 8;
      short8 a0 = lds_frag(&wa[buf][(wm * 64 + l31) * STR + ko]);
      short8 a1 = lds_frag(&wa[buf][(wm * 64 + 32 + l31) * STR + ko]);
      short8 b0 = lds_frag(&xb[buf][(wn * 64 + l31) * STR + ko]);
      short8 b1 = lds_frag(&xb[buf][(wn * 64 + 32 + l31) * STR + ko]);
      acc[0][0] = __builtin_amdgcn_mfma_f32_32x32x16_bf16(a0, b0, acc[0][0], 0, 0, 0);
      acc[0][1] = __builtin_amdgcn_mfma_f32_32x32x16_bf16(a0, b1, acc[0][1], 0, 0, 0);
      acc[1][0] = __builtin_amdgcn_mfma_f32_32x32x16_bf16(a1, b0, acc[1][0], 0, 0, 0);
      acc[1][1] = __builtin_amdgcn_mfma_f32_32x32x16_bf16(a1, b1, acc[1][1], 0, 0, 0);
    }

    if (kc < 7) { STOREK(buf ^ 1); }
    __syncthreads();
  }
  #undef LOADK
  #undef STOREK

  if constexpr (MODE == 0) {
    const int hh = (o0 >> 6) + wm;  // o = o0 + wm*64 + am*32 + row
    // am=0: q+k -> token-major qkT[b][hh][token][cc]
    #pragma unroll
    for (int bn = 0; bn < 2; ++bn) {
      int n = nloc + wn * 64 + bn * 32 + l31;
      unsigned short* row = qkT + (((size_t)b * NH + hh) * N_ + n) * 32;
      #pragma unroll
      for (int qd = 0; qd < 4; ++qd) {
        int cc0 = 8 * qd + 4 * lh;
        ushort4 rv;
        rv.x = f2bf(acc[0][bn][4 * qd + 0] + bias[hh * 64 + cc0 + 0]);
        rv.y = f2bf(acc[0][bn][4 * qd + 1] + bias[hh * 64 + cc0 + 1]);
        rv.z = f2bf(acc[0][bn][4 * qd + 2] + bias[hh * 64 + cc0 + 2]);
        rv.w = f2bf(acc[0][bn][4 * qd + 3] + bias[hh * 64 + cc0 + 3]);
        *(ushort4*)(row + cc0) = rv;
      }
    }
    // am=1: v -> planar bf16 vbuf[b][hh*32+d][n]
    #pragma unroll
    for (int r = 0; r < 16; ++r) {
      int d = (r & 3) + 8 * (r >> 2) + 4 * lh;
      float bo = bias[hh * 64 + 32 + d];
      unsigned short* vrow =
          vbuf + ((size_t)b * C_ + hh * 32 + d) * N_ + nloc + wn * 64 + l31;
      #pragma unroll
      for (int bn = 0; bn < 2; ++bn)
        vrow[bn * 32] = f2bf(acc[1][bn][r] + bo);
    }
  } else {
    #pragma unroll
    for (int am = 0; am < 2; ++am) {
      #pragma unroll
      for (int r = 0; r < 16; ++r) {
        int o = o0 + wm * 64 + am * 32 + (r & 3) + 8 * (r >> 2) + 4 * lh;
        float bo = bias[o];
        float* orow = outf + ((size_t)b * C_ + o) * N_ + nloc + wn * 64 + l31;
        #pragma unroll
        for (int bn = 0; bn < 2; ++bn)
          orow[bn * 32] = acc[am][bn][r] + bo;
      }
    }
  }
}

// ---------------------------------------------------------------------------
// depthwise 3x3 + BN on v (bf16 planar) -> posenc bf16 planar.
// ---------------------------------------------------------------------------
__global__ __launch_bounds__(256) void dwconv_bn(
    const unsigned short* __restrict__ vbuf, const float* __restrict__ pw,
    const float* __restrict__ gamma, const float* __restrict__ beta,
    const float* __restrict__ mean, const float* __restrict__ var,
    unsigned short* __restrict__ posb)
{
  __shared__ float t[34][34];
  const int c = blockIdx.x, b = blockIdx.y;
  const int tid = threadIdx.x;
  const unsigned short* vp = vbuf + ((size_t)b * C_ + c) * N_;

  #pragma unroll
  for (int r = 0; r < 4; ++r) {
    int idx = r * 256 + tid;
    t[(idx >> 5) + 1][(idx & 31) + 1] = bf2f(vp[idx]);
  }
  if (tid < 34) {
    t[0][tid] = 0.f; t[33][tid] = 0.f;
    t[tid][0] = 0.f; t[tid][33] = 0.f;
  }
  __syncthreads();

  float w9[9];
  #pragma unroll
  for (int i = 0; i < 9; ++i) w9[i] = pw[c * 9 + i];
  float inv = gamma[c] * rsqrtf(var[c] + BN_EPS);
  float add = beta[c] - mean[c] * inv;

  unsigned short* op = posb + ((size_t)b * C_ + c) * N_;
  #pragma unroll
  for (int r = 0; r < 4; ++r) {
    int idx = r * 256 + tid;
    int y = idx >> 5, x = idx & 31;
    float s = 0.f;
    #pragma unroll
    for (int dy = 0; dy < 3; ++dy)
      #pragma unroll
      for (int dx = 0; dx < 3; ++dx)
        s += t[y + dy][x + dx] * w9[dy * 3 + dx];
    op[idx] = f2bf(s * inv + add);
  }
}

// ---------------------------------------------------------------------------
// MFMA attention: 64 queries/wave (2 Q frags share every K/V frag), LDS K/V
// double-buffered with reg-prefetch + one barrier/chunk, conflict-free
// strides (K row 28 shorts, V row 140), permlane32_swap P-transpose.
// Epilogue adds posenc (bf16) and writes token-major bf16 vattnT.
// ---------------------------------------------------------------------------
__global__ __launch_bounds__(256) void attn_mfma(
    const unsigned short* __restrict__ qkT, const unsigned short* __restrict__ vbuf,
    const unsigned short* __restrict__ posb, unsigned short* __restrict__ vattnT)
{
  __shared__ __align__(8) unsigned short k_lds[2][128 * 28];
  __shared__ __align__(8) unsigned short v_lds[2][32 * 140];

  const int tid = threadIdx.x;
  const int wave = tid >> 6, lane = tid & 63;
  const int l31 = lane & 31, lh = lane >> 5;
  const int h = blockIdx.y, b = blockIdx.z;
  const int qbase = blockIdx.x * 256 + wave * 64;

  const unsigned short* qkb = qkT + ((size_t)b * NH + h) * N_ * 32;
  const unsigned short* vhead = vbuf + ((size_t)b * C_ + h * HD) * N_;

  const int skey = tid >> 1, shalf = tid & 1;   // K: 128 keys x 2 octs
  const int svd = tid >> 3, svseg = tid & 7;    // V: 32 d x 8 segs of 16 keys

  // Q fragments: scale pre-folded by fold_weights -> direct 16B loads
  short8 qfA = lds_frag(qkb + (size_t)(qbase + l31) * 32 + lh * 8);        // global, same union trick
  short8 qfB = lds_frag(qkb + (size_t)(qbase + 32 + l31) * 32 + lh * 8);

  uint4 gk, gv0, gv1;
  #define LOADC(kc)                                                             \
    gk  = *(const uint4*)(qkb + (size_t)((kc) + skey) * 32 + 16 + shalf * 8);   \
    gv0 = *(const uint4*)(vhead + (size_t)svd * N_ + (kc) + svseg * 16);        \
    gv1 = *(const uint4*)(vhead + (size_t)svd * N_ + (kc) + svseg * 16 + 8);
  #define STOREC(bufi)                                        \
    lds_store16(&k_lds[bufi][skey * 28 + shalf * 8], gk);     \
    lds_store16(&v_lds[bufi][svd * 140 + svseg * 16], gv0);   \
    lds_store16(&v_lds[bufi][svd * 140 + svseg * 16 + 8], gv1);

  LOADC(0);
  STOREC(0);
  __syncthreads();

  float16 oaccA = zero16(), oaccB = zero16();
  float lsA[4] = {0.f, 0.f, 0.f, 0.f}, lsB[4] = {0.f, 0.f, 0.f, 0.f};

  for (int c = 0; c < 8; ++c) {
    const int buf = c & 1;
    if (c < 7) { LOADC((c + 1) * 128); }

    #pragma unroll
    for (int t = 0; t < 4; ++t) {
      const int key0 = t * 32;
      short8 kf = lds_frag(&k_lds[buf][(key0 + l31) * 28 + lh * 8]);
      float16 stA = __builtin_amdgcn_mfma_f32_32x32x16_bf16(kf, qfA, zero16(), 0, 0, 0);
      float16 stB = __builtin_amdgcn_mfma_f32_32x32x16_bf16(kf, qfB, zero16(), 0, 0, 0);

      unsigned int uA[8], uB[8];
      #pragma unroll
      for (int q = 0; q < 8; ++q) {
        float pe = fast_exp2(stA[2 * q]);
        float po = fast_exp2(stA[2 * q + 1]);
        lsA[q & 3] += pe + po;
        uA[q] = pack_bf16_trunc(pe, po);
      }
      #pragma unroll
      for (int q = 0; q < 8; ++q) {
        float pe = fast_exp2(stB[2 * q]);
        float po = fast_exp2(stB[2 * q + 1]);
        lsB[q & 3] += pe + po;
        uB[q] = pack_bf16_trunc(pe, po);
      }

      #pragma unroll
      for (int f = 0; f < 2; ++f) {
        short8 vf = lds_frag(&v_lds[buf][l31 * 140 + key0 + f * 16 + lh * 8]);
        const int q0 = f * 4;
        {
          unsigned int a0 = uA[q0], a2 = uA[q0 + 2]; pl32(a0, a2);
          unsigned int a1 = uA[q0 + 1], a3 = uA[q0 + 3]; pl32(a1, a3);
          union { unsigned int w[4]; short8 s; } bf;
          bf.w[0] = a0; bf.w[1] = a1; bf.w[2] = a2; bf.w[3] = a3;
          oaccA = __builtin_amdgcn_mfma_f32_32x32x16_bf16(vf, bf.s, oaccA, 0, 0, 0);
        }
        {
          unsigned int a0 = uB[q0], a2 = uB[q0 + 2]; pl32(a0, a2);
          unsigned int a1 = uB[q0 + 1], a3 = uB[q0 + 3]; pl32(a1, a3);
          union { unsigned int w[4]; short8 s; } bf;
          bf.w[0] = a0; bf.w[1] = a1; bf.w[2] = a2; bf.w[3] = a3;
          oaccB = __builtin_amdgcn_mfma_f32_32x32x16_bf16(vf, bf.s, oaccB, 0, 0, 0);
        }
      }
    }

    if (c < 7) { STOREC(buf ^ 1); }
    __syncthreads();
  }
  #undef LOADC
  #undef STOREC

  float lsumA = (lsA[0] + lsA[1]) + (lsA[2] + lsA[3]);
  float lsumB = (lsB[0] + lsB[1]) + (lsB[2] + lsB[3]);
  lsumA += __shfl_xor(lsumA, 32, 64);
  lsumB += __shfl_xor(lsumB, 32, 64);
  const float linvA = 1.f / lsumA, linvB = 1.f / lsumB;

  // epilogue: two query groups, permlane transpose to token-major bf16
  #pragma unroll
  for (int g = 0; g < 2; ++g) {
    const float16& oacc = g ? oaccB : oaccA;
    const float linv = g ? linvB : linvA;
    const int token = qbase + g * 32 + l31;
    float val[16];
    #pragma unroll
    for (int r = 0; r < 16; ++r) {
      int d = (r & 3) + 8 * (r >> 2) + 4 * lh;
      val[r] = oacc[r] * linv +
               bf2f(posb[((size_t)b * C_ + h * HD + d) * N_ + token]);
    }
    unsigned int u[8];
    #pragma unroll
    for (int m = 0; m < 8; ++m) u[m] = pack_bf16_rne(val[2 * m], val[2 * m + 1]);
    pl32(u[0], u[4]); pl32(u[1], u[5]); pl32(u[2], u[6]); pl32(u[3], u[7]);
    unsigned short* row = vattnT + ((size_t)b * N_ + token) * C_ + h * HD + lh * 16;
    *(uint4*)(row)     = make_uint4(u[0], u[1], u[4], u[5]);
    *(uint4*)(row + 8) = make_uint4(u[2], u[3], u[6], u[7]);
  }
}

// ---------------------------------------------------------------------------
extern "C" void kernel_launch(void* const* d_in, const int* in_sizes, int n_in,
                              void* d_out, int out_size, void* d_ws, size_t ws_size,
                              hipStream_t stream) {
  const float* x          = (const float*)d_in[0];
  const float* qkv_w      = (const float*)d_in[1];
  const float* qkv_gamma  = (const float*)d_in[2];
  const float* qkv_beta   = (const float*)d_in[3];
  const float* qkv_mean   = (const float*)d_in[4];
  const float* qkv_var    = (const float*)d_in[5];
  const float* pe_w       = (const float*)d_in[6];
  const float* pe_gamma   = (const float*)d_in[7];
  const float* pe_beta    = (const float*)d_in[8];
  const float* pe_mean    = (const float*)d_in[9];
  const float* pe_var     = (const float*)d_in[10];
  const float* proj_w     = (const float*)d_in[11];
  const float* proj_gamma = (const float*)d_in[12];
  const float* proj_beta  = (const float*)d_in[13];
  const float* proj_mean  = (const float*)d_in[14];
  const float* proj_var   = (const float*)d_in[15];
  float* out = (float*)d_out;

  char* ws = (char*)d_ws;
  unsigned short* qkT = (unsigned short*)ws;
  ws += (size_t)B_ * NH * N_ * 32 * sizeof(unsigned short);
  unsigned short* vbuf = (unsigned short*)ws;
  ws += (size_t)B_ * C_ * N_ * sizeof(unsigned short);
  unsigned short* xT = (unsigned short*)ws;
  ws += (size_t)B_ * N_ * C_ * sizeof(unsigned short);
  unsigned short* vattnT = (unsigned short*)ws;
  ws += (size_t)B_ * N_ * C_ * sizeof(unsigned short);
  unsigned short* posb = (unsigned short*)ws;
  ws += (size_t)B_ * C_ * N_ * sizeof(unsigned short);
  unsigned short* wq = (unsigned short*)ws;
  ws += (size_t)QKV_OUT_ * C_ * sizeof(unsigned short);
  unsigned short* wp = (unsigned short*)ws;
  ws += (size_t)C_ * C_ * sizeof(unsigned short);
  float* biasq = (float*)ws; ws += QKV_OUT_ * sizeof(float);
  float* biasp = (float*)ws;

  fold_weights<<<dim3(QKV_OUT_ + C_), 256, 0, stream>>>(
      qkv_w, qkv_gamma, qkv_beta, qkv_mean, qkv_var,
      proj_w, proj_gamma, proj_beta, proj_mean, proj_var,
      wq, biasq, wp, biasp);
  transpose_x<<<dim3(16, 4, 16), 256, 0, stream>>>(x, xT);

  gemm_tiled<0><<<dim3(128, 4), 256, 0, stream>>>(
      xT, wq, biasq, qkT, vbuf, nullptr);

  dwconv_bn<<<dim3(C_, B_), 256, 0, stream>>>(
      vbuf, pe_w, pe_gamma, pe_beta, pe_mean, pe_var, posb);

  attn_mfma<<<dim3(4, NH, B_), 256, 0, stream>>>(qkT, vbuf, posb, vattnT);

  gemm_tiled<1><<<dim3(128, 2), 256, 0, stream>>>(
      vattnT, wp, biasp, nullptr, nullptr, out);
}

// Round 8
// 156.495 us; speedup vs baseline: 1.2514x; 1.0307x over previous
//
#include <hip/hip_runtime.h>

#define B_ 16
#define C_ 256
#define N_ 1024
#define NH 8
#define HD 32
#define KD 16
#define QKV_OUT_ 512
#define BN_EPS 1e-3f
// softmax scale * log2(e), pre-folded into the q-channel weights
#define SCALE2_ (0.25f * 1.44269504088896f)

typedef __attribute__((ext_vector_type(8))) short short8;
typedef __attribute__((ext_vector_type(16))) float float16;

__device__ inline unsigned short f2bf(float f) {
  unsigned int u = __float_as_uint(f);
  return (unsigned short)((u + 0x7FFF + ((u >> 16) & 1)) >> 16);  // RNE
}
__device__ inline float bf2f(unsigned short s) {
  return __uint_as_float(((unsigned int)s) << 16);
}
__device__ inline float16 zero16() {
  float16 z;
  #pragma unroll
  for (int i = 0; i < 16; ++i) z[i] = 0.f;
  return z;
}
__device__ inline unsigned int pack_bf16_trunc(float a, float b) {
  return __builtin_amdgcn_perm(__float_as_uint(b), __float_as_uint(a), 0x07060302u);
}
__device__ inline unsigned int pack_bf16_rne(float a, float b) {
  return (unsigned int)f2bf(a) | ((unsigned int)f2bf(b) << 16);
}
__device__ inline float fast_exp2(float x) {
#if __has_builtin(__builtin_amdgcn_exp2f)
  return __builtin_amdgcn_exp2f(x);
#else
  return exp2f(x);
#endif
}
// permlane32_swap: a' = {a.lo, b.lo}, b' = {a.hi, b.hi}
__device__ inline void pl32(unsigned int& a, unsigned int& b) {
#if __has_builtin(__builtin_amdgcn_permlane32_swap)
  typedef __attribute__((ext_vector_type(2))) int int2v;
  int2v r = __builtin_amdgcn_permlane32_swap((int)a, (int)b, false, false);
  a = (unsigned int)r[0];
  b = (unsigned int)r[1];
#else
  unsigned int ea = (unsigned int)__shfl_xor((int)a, 32, 64);
  unsigned int eb = (unsigned int)__shfl_xor((int)b, 32, 64);
  bool hi = (threadIdx.x & 32) != 0;
  unsigned int an = hi ? eb : a;
  unsigned int bn = hi ? b : ea;
  a = an; b = bn;
#endif
}
__device__ inline short8 lds_frag(const unsigned short* p) {
  union { uint2 u[2]; short8 s; } r;
  r.u[0] = *(const uint2*)p;
  r.u[1] = *(const uint2*)(p + 4);
  return r.s;
}
__device__ inline void lds_store16(unsigned short* p, uint4 v) {
  *(uint2*)p = make_uint2(v.x, v.y);
  *(uint2*)(p + 4) = make_uint2(v.z, v.w);
}

// ---------------------------------------------------------------------------
// Fold BN into conv weights (bf16) + bias.  q-channels (o%64 < 16) also get
// SCALE2_ folded so attention uses raw exp2 with no Q repack.
// ---------------------------------------------------------------------------
__global__ __launch_bounds__(256) void fold_weights(
    const float* __restrict__ qkv_w, const float* __restrict__ qg,
    const float* __restrict__ qb, const float* __restrict__ qm,
    const float* __restrict__ qv,
    const float* __restrict__ proj_w, const float* __restrict__ pg,
    const float* __restrict__ pb, const float* __restrict__ pm,
    const float* __restrict__ pv,
    unsigned short* __restrict__ wq, float* __restrict__ biasq,
    unsigned short* __restrict__ wp, float* __restrict__ biasp)
{
  const int o = blockIdx.x, c = threadIdx.x;
  if (o < QKV_OUT_) {
    float s = ((o & 63) < 16) ? SCALE2_ : 1.f;
    float inv = qg[o] * rsqrtf(qv[o] + BN_EPS) * s;
    wq[o * C_ + c] = f2bf(qkv_w[o * C_ + c] * inv);
    if (c == 0) biasq[o] = qb[o] * s - qm[o] * inv;
  } else {
    int oo = o - QKV_OUT_;
    float inv = pg[oo] * rsqrtf(pv[oo] + BN_EPS);
    wp[oo * C_ + c] = f2bf(proj_w[oo * C_ + c] * inv);
    if (c == 0) biasp[oo] = pb[oo] - pm[oo] * inv;
  }
}

// ---------------------------------------------------------------------------
// qkv GEMM with FUSED transpose: B staged directly from planar f32 x
// (coalesced scalar loads along tokens, RNE-packed to bf16 in registers).
// Tile 128(o) x 128(tok), BK=32, double-buffered LDS, stride 44 shorts
// (22 dw == 2 mod 4 -> 2-way bank aliasing = free), 1 barrier / K-step.
// Epilogue: q,k -> token-major qkT[b][h][token][32]; v -> planar bf16 vbuf.
// ---------------------------------------------------------------------------
__global__ __launch_bounds__(256) void gemm_qkv(
    const float* __restrict__ x, const unsigned short* __restrict__ wq,
    const float* __restrict__ bias,
    unsigned short* __restrict__ qkT, unsigned short* __restrict__ vbuf)
{
  constexpr int STR = 44;
  __shared__ __align__(8) unsigned short wa[2][128 * STR];
  __shared__ __align__(8) unsigned short xb[2][128 * STR];
  const int tid = threadIdx.x;
  const int wave = tid >> 6, lane = tid & 63, l31 = lane & 31, lh = lane >> 5;
  const int wm = wave & 1, wn = wave >> 1;
  const int b = blockIdx.x >> 3, nloc = (blockIdx.x & 7) * 128;
  const int o0 = blockIdx.y * 128;

  // A staging: 512 slots of 16B; thread covers slots tid, tid+256
  const int r0 = tid >> 2, oc0 = (tid & 3) * 8;
  const int r1 = r0 + 64;
  // B staging: token tok, channel half chalf (16 ch), 16 scalar f32 loads
  const int tok = tid & 127, chalf = (tid >> 7) * 16;
  const float* xbase = x + (size_t)b * C_ * N_ + nloc + tok;

  uint4 ga0, ga1;
  float nb[16];

  auto loadk = [&](int kc) {
    ga0 = *(const uint4*)(wq + (size_t)(o0 + r0) * C_ + kc * 32 + oc0);
    ga1 = *(const uint4*)(wq + (size_t)(o0 + r1) * C_ + kc * 32 + oc0);
    #pragma unroll
    for (int j = 0; j < 16; ++j)
      nb[j] = xbase[(size_t)(kc * 32 + chalf + j) * N_];
  };
  auto storek = [&](int bufi) {
    lds_store16(&wa[bufi][r0 * STR + oc0], ga0);
    lds_store16(&wa[bufi][r1 * STR + oc0], ga1);
    unsigned int pk[8];
    #pragma unroll
    for (int q = 0; q < 8; ++q) pk[q] = pack_bf16_rne(nb[2 * q], nb[2 * q + 1]);
    lds_store16(&xb[bufi][tok * STR + chalf], make_uint4(pk[0], pk[1], pk[2], pk[3]));
    lds_store16(&xb[bufi][tok * STR + chalf + 8], make_uint4(pk[4], pk[5], pk[6], pk[7]));
  };

  float16 acc[2][2];
  #pragma unroll
  for (int i = 0; i < 2; ++i)
    #pragma unroll
    for (int j = 0; j < 2; ++j) acc[i][j] = zero16();

  loadk(0);
  storek(0);
  __syncthreads();

  for (int kc = 0; kc < 8; ++kc) {
    const int buf = kc & 1;
    if (kc < 7) loadk(kc + 1);   // global loads land during MFMA

    #pragma unroll
    for (int ks = 0; ks < 2; ++ks) {
      const int ko = ks * 16 + lh * 8;
      short8 a0 = lds_frag(&wa[buf][(wm * 64 + l31) * STR + ko]);
      short8 a1 = lds_frag(&wa[buf][(wm * 64 + 32 + l31) * STR + ko]);
      short8 b0 = lds_frag(&xb[buf][(wn * 64 + l31) * STR + ko]);
      short8 b1 = lds_frag(&xb[buf][(wn * 64 + 32 + l31) * STR + ko]);
      acc[0][0] = __builtin_amdgcn_mfma_f32_32x32x16_bf16(a0, b0, acc[0][0], 0, 0, 0);
      acc[0][1] = __builtin_amdgcn_mfma_f32_32x32x16_bf16(a0, b1, acc[0][1], 0, 0, 0);
      acc[1][0] = __builtin_amdgcn_mfma_f32_32x32x16_bf16(a1, b0, acc[1][0], 0, 0, 0);
      acc[1][1] = __builtin_amdgcn_mfma_f32_32x32x16_bf16(a1, b1, acc[1][1], 0, 0, 0);
    }

    if (kc < 7) storek(buf ^ 1);
    __syncthreads();
  }

  const int hh = (o0 >> 6) + wm;  // o = o0 + wm*64 + am*32 + row
  // am=0: q+k -> token-major qkT[b][hh][token][cc]
  #pragma unroll
  for (int bn = 0; bn < 2; ++bn) {
    int n = nloc + wn * 64 + bn * 32 + l31;
    unsigned short* row = qkT + (((size_t)b * NH + hh) * N_ + n) * 32;
    #pragma unroll
    for (int qd = 0; qd < 4; ++qd) {
      int cc0 = 8 * qd + 4 * lh;
      ushort4 rv;
      rv.x = f2bf(acc[0][bn][4 * qd + 0] + bias[hh * 64 + cc0 + 0]);
      rv.y = f2bf(acc[0][bn][4 * qd + 1] + bias[hh * 64 + cc0 + 1]);
      rv.z = f2bf(acc[0][bn][4 * qd + 2] + bias[hh * 64 + cc0 + 2]);
      rv.w = f2bf(acc[0][bn][4 * qd + 3] + bias[hh * 64 + cc0 + 3]);
      *(ushort4*)(row + cc0) = rv;
    }
  }
  // am=1: v -> planar bf16 vbuf[b][hh*32+d][n]
  #pragma unroll
  for (int r = 0; r < 16; ++r) {
    int d = (r & 3) + 8 * (r >> 2) + 4 * lh;
    float bo = bias[hh * 64 + 32 + d];
    unsigned short* vrow =
        vbuf + ((size_t)b * C_ + hh * 32 + d) * N_ + nloc + wn * 64 + l31;
    #pragma unroll
    for (int bn = 0; bn < 2; ++bn)
      vrow[bn * 32] = f2bf(acc[1][bn][r] + bo);
  }
}

// ---------------------------------------------------------------------------
// proj GEMM: token-major bf16 in -> planar f32 out.  Same tile/pipeline.
// ---------------------------------------------------------------------------
__global__ __launch_bounds__(256) void gemm_proj(
    const unsigned short* __restrict__ inT, const unsigned short* __restrict__ wfold,
    const float* __restrict__ bias, float* __restrict__ outf)
{
  constexpr int STR = 44;
  __shared__ __align__(8) unsigned short wa[2][128 * STR];
  __shared__ __align__(8) unsigned short xb[2][128 * STR];
  const int tid = threadIdx.x;
  const int wave = tid >> 6, lane = tid & 63, l31 = lane & 31, lh = lane >> 5;
  const int wm = wave & 1, wn = wave >> 1;
  const int n0g = blockIdx.x * 128;
  const int o0 = blockIdx.y * 128;
  const int b = n0g >> 10, nloc = n0g & 1023;

  const int r0 = tid >> 2, oc0 = (tid & 3) * 8;
  const int r1 = r0 + 64;

  float16 acc[2][2];
  #pragma unroll
  for (int i = 0; i < 2; ++i)
    #pragma unroll
    for (int j = 0; j < 2; ++j) acc[i][j] = zero16();

  uint4 ga0, ga1, gb0, gb1;
  auto loadk = [&](int kc) {
    ga0 = *(const uint4*)(wfold + (size_t)(o0 + r0) * C_ + kc * 32 + oc0);
    ga1 = *(const uint4*)(wfold + (size_t)(o0 + r1) * C_ + kc * 32 + oc0);
    gb0 = *(const uint4*)(inT + (size_t)(n0g + r0) * C_ + kc * 32 + oc0);
    gb1 = *(const uint4*)(inT + (size_t)(n0g + r1) * C_ + kc * 32 + oc0);
  };
  auto storek = [&](int bufi) {
    lds_store16(&wa[bufi][r0 * STR + oc0], ga0);
    lds_store16(&wa[bufi][r1 * STR + oc0], ga1);
    lds_store16(&xb[bufi][r0 * STR + oc0], gb0);
    lds_store16(&xb[bufi][r1 * STR + oc0], gb1);
  };

  loadk(0);
  storek(0);
  __syncthreads();

  for (int kc = 0; kc < 8; ++kc) {
    const int buf = kc & 1;
    if (kc < 7) loadk(kc + 1);

    #pragma unroll
    for (int ks = 0; ks < 2; ++ks) {
      const int ko = ks * 16 + lh * 8;
      short8 a0 = lds_frag(&wa[buf][(wm * 64 + l31) * STR + ko]);
      short8 a1 = lds_frag(&wa[buf][(wm * 64 + 32 + l31) * STR + ko]);
      short8 b0 = lds_frag(&xb[buf][(wn * 64 + l31) * STR + ko]);
      short8 b1 = lds_frag(&xb[buf][(wn * 64 + 32 + l31) * STR + ko]);
      acc[0][0] = __builtin_amdgcn_mfma_f32_32x32x16_bf16(a0, b0, acc[0][0], 0, 0, 0);
      acc[0][1] = __builtin_amdgcn_mfma_f32_32x32x16_bf16(a0, b1, acc[0][1], 0, 0, 0);
      acc[1][0] = __builtin_amdgcn_mfma_f32_32x32x16_bf16(a1, b0, acc[1][0], 0, 0, 0);
      acc[1][1] = __builtin_amdgcn_mfma_f32_32x32x16_bf16(a1, b1, acc[1][1], 0, 0, 0);
    }

    if (kc < 7) storek(buf ^ 1);
    __syncthreads();
  }

  #pragma unroll
  for (int am = 0; am < 2; ++am) {
    #pragma unroll
    for (int r = 0; r < 16; ++r) {
      int o = o0 + wm * 64 + am * 32 + (r & 3) + 8 * (r >> 2) + 4 * lh;
      float bo = bias[o];
      float* orow = outf + ((size_t)b * C_ + o) * N_ + nloc + wn * 64 + l31;
      #pragma unroll
      for (int bn = 0; bn < 2; ++bn)
        orow[bn * 32] = acc[am][bn][r] + bo;
    }
  }
}

// ---------------------------------------------------------------------------
// depthwise 3x3 + BN on v (bf16 planar) -> posenc bf16 planar.
// ---------------------------------------------------------------------------
__global__ __launch_bounds__(256) void dwconv_bn(
    const unsigned short* __restrict__ vbuf, const float* __restrict__ pw,
    const float* __restrict__ gamma, const float* __restrict__ beta,
    const float* __restrict__ mean, const float* __restrict__ var,
    unsigned short* __restrict__ posb)
{
  __shared__ float t[34][34];
  const int c = blockIdx.x, b = blockIdx.y;
  const int tid = threadIdx.x;
  const unsigned short* vp = vbuf + ((size_t)b * C_ + c) * N_;

  #pragma unroll
  for (int r = 0; r < 4; ++r) {
    int idx = r * 256 + tid;
    t[(idx >> 5) + 1][(idx & 31) + 1] = bf2f(vp[idx]);
  }
  if (tid < 34) {
    t[0][tid] = 0.f; t[33][tid] = 0.f;
    t[tid][0] = 0.f; t[tid][33] = 0.f;
  }
  __syncthreads();

  float w9[9];
  #pragma unroll
  for (int i = 0; i < 9; ++i) w9[i] = pw[c * 9 + i];
  float inv = gamma[c] * rsqrtf(var[c] + BN_EPS);
  float add = beta[c] - mean[c] * inv;

  unsigned short* op = posb + ((size_t)b * C_ + c) * N_;
  #pragma unroll
  for (int r = 0; r < 4; ++r) {
    int idx = r * 256 + tid;
    int y = idx >> 5, x = idx & 31;
    float s = 0.f;
    #pragma unroll
    for (int dy = 0; dy < 3; ++dy)
      #pragma unroll
      for (int dx = 0; dx < 3; ++dx)
        s += t[y + dy][x + dx] * w9[dy * 3 + dx];
    op[idx] = f2bf(s * inv + add);
  }
}

// ---------------------------------------------------------------------------
// MFMA attention, 32 q/wave, grid (bh, qt) so all 8 q-tiles of one (b,h)
// land on the SAME XCD (linear ids differ by 128 == 0 mod 8) -> K/V L2-hot.
// LDS K/V double-buffered, reg-prefetch, 1 barrier/chunk, conflict-free
// strides; P transposed in-register via permlane32_swap.
// ---------------------------------------------------------------------------
__global__ __launch_bounds__(256) void attn_mfma(
    const unsigned short* __restrict__ qkT, const unsigned short* __restrict__ vbuf,
    const unsigned short* __restrict__ posb, unsigned short* __restrict__ vattnT)
{
  __shared__ __align__(8) unsigned short k_lds[2][128 * 28];
  __shared__ __align__(8) unsigned short v_lds[2][32 * 140];

  const int tid = threadIdx.x;
  const int wave = tid >> 6, lane = tid & 63;
  const int l31 = lane & 31, lh = lane >> 5;
  const int b = blockIdx.x >> 3, h = blockIdx.x & 7;
  const int qbase = blockIdx.y * 128 + wave * 32;

  const unsigned short* qkb = qkT + ((size_t)b * NH + h) * N_ * 32;
  const unsigned short* vhead = vbuf + ((size_t)b * C_ + h * HD) * N_;

  const int skey = tid >> 1, shalf = tid & 1;   // K: 128 keys x 2 16B segs
  const int svd = tid >> 3, svseg = tid & 7;    // V: 32 d x 8 segs of 32B

  // Q fragment (B of S^T): scale pre-folded -> direct 16B load
  short8 qf = lds_frag(qkb + (size_t)(qbase + l31) * 32 + lh * 8);

  uint4 gk, gv0, gv1;
  auto loadc = [&](int kc) {
    gk  = *(const uint4*)(qkb + (size_t)(kc + skey) * 32 + 16 + shalf * 8);
    gv0 = *(const uint4*)(vhead + (size_t)svd * N_ + kc + svseg * 16);
    gv1 = *(const uint4*)(vhead + (size_t)svd * N_ + kc + svseg * 16 + 8);
  };
  auto storec = [&](int bufi) {
    lds_store16(&k_lds[bufi][skey * 28 + shalf * 8], gk);
    lds_store16(&v_lds[bufi][svd * 140 + svseg * 16], gv0);
    lds_store16(&v_lds[bufi][svd * 140 + svseg * 16 + 8], gv1);
  };

  loadc(0);
  storec(0);
  __syncthreads();

  float16 oacc = zero16();
  float ls[4] = {0.f, 0.f, 0.f, 0.f};

  for (int c = 0; c < 8; ++c) {
    const int buf = c & 1;
    if (c < 7) loadc((c + 1) * 128);

    #pragma unroll
    for (int t = 0; t < 4; ++t) {
      const int key0 = t * 32;
      short8 kf = lds_frag(&k_lds[buf][(key0 + l31) * 28 + lh * 8]);
      float16 st = __builtin_amdgcn_mfma_f32_32x32x16_bf16(kf, qf, zero16(), 0, 0, 0);

      unsigned int u[8];
      #pragma unroll
      for (int q = 0; q < 8; ++q) {
        float pe = fast_exp2(st[2 * q]);
        float po = fast_exp2(st[2 * q + 1]);
        ls[q & 3] += pe + po;
        u[q] = pack_bf16_trunc(pe, po);
      }

      #pragma unroll
      for (int f = 0; f < 2; ++f) {
        short8 vf = lds_frag(&v_lds[buf][l31 * 140 + key0 + f * 16 + lh * 8]);
        const int q0 = f * 4;
        unsigned int a0 = u[q0], a2 = u[q0 + 2]; pl32(a0, a2);
        unsigned int a1 = u[q0 + 1], a3 = u[q0 + 3]; pl32(a1, a3);
        union { unsigned int w[4]; short8 s; } bf;
        bf.w[0] = a0; bf.w[1] = a1; bf.w[2] = a2; bf.w[3] = a3;
        oacc = __builtin_amdgcn_mfma_f32_32x32x16_bf16(vf, bf.s, oacc, 0, 0, 0);
      }
    }

    if (c < 7) storec(buf ^ 1);
    __syncthreads();
  }

  float lsum = (ls[0] + ls[1]) + (ls[2] + ls[3]);
  lsum += __shfl_xor(lsum, 32, 64);
  const float linv = 1.f / lsum;

  // epilogue: val = O/l + posenc, permlane transpose to token-major bf16
  const int token = qbase + l31;
  float val[16];
  #pragma unroll
  for (int r = 0; r < 16; ++r) {
    int d = (r & 3) + 8 * (r >> 2) + 4 * lh;
    val[r] = oacc[r] * linv +
             bf2f(posb[((size_t)b * C_ + h * HD + d) * N_ + token]);
  }
  unsigned int u[8];
  #pragma unroll
  for (int m = 0; m < 8; ++m) u[m] = pack_bf16_rne(val[2 * m], val[2 * m + 1]);
  pl32(u[0], u[4]); pl32(u[1], u[5]); pl32(u[2], u[6]); pl32(u[3], u[7]);
  unsigned short* row = vattnT + ((size_t)b * N_ + token) * C_ + h * HD + lh * 16;
  *(uint4*)(row)     = make_uint4(u[0], u[1], u[4], u[5]);
  *(uint4*)(row + 8) = make_uint4(u[2], u[3], u[6], u[7]);
}

// ---------------------------------------------------------------------------
extern "C" void kernel_launch(void* const* d_in, const int* in_sizes, int n_in,
                              void* d_out, int out_size, void* d_ws, size_t ws_size,
                              hipStream_t stream) {
  const float* x          = (const float*)d_in[0];
  const float* qkv_w      = (const float*)d_in[1];
  const float* qkv_gamma  = (const float*)d_in[2];
  const float* qkv_beta   = (const float*)d_in[3];
  const float* qkv_mean   = (const float*)d_in[4];
  const float* qkv_var    = (const float*)d_in[5];
  const float* pe_w       = (const float*)d_in[6];
  const float* pe_gamma   = (const float*)d_in[7];
  const float* pe_beta    = (const float*)d_in[8];
  const float* pe_mean    = (const float*)d_in[9];
  const float* pe_var     = (const float*)d_in[10];
  const float* proj_w     = (const float*)d_in[11];
  const float* proj_gamma = (const float*)d_in[12];
  const float* proj_beta  = (const float*)d_in[13];
  const float* proj_mean  = (const float*)d_in[14];
  const float* proj_var   = (const float*)d_in[15];
  float* out = (float*)d_out;

  char* ws = (char*)d_ws;
  unsigned short* qkT = (unsigned short*)ws;
  ws += (size_t)B_ * NH * N_ * 32 * sizeof(unsigned short);
  unsigned short* vbuf = (unsigned short*)ws;
  ws += (size_t)B_ * C_ * N_ * sizeof(unsigned short);
  unsigned short* vattnT = (unsigned short*)ws;
  ws += (size_t)B_ * N_ * C_ * sizeof(unsigned short);
  unsigned short* posb = (unsigned short*)ws;
  ws += (size_t)B_ * C_ * N_ * sizeof(unsigned short);
  unsigned short* wq = (unsigned short*)ws;
  ws += (size_t)QKV_OUT_ * C_ * sizeof(unsigned short);
  unsigned short* wp = (unsigned short*)ws;
  ws += (size_t)C_ * C_ * sizeof(unsigned short);
  float* biasq = (float*)ws; ws += QKV_OUT_ * sizeof(float);
  float* biasp = (float*)ws;

  fold_weights<<<dim3(QKV_OUT_ + C_), 256, 0, stream>>>(
      qkv_w, qkv_gamma, qkv_beta, qkv_mean, qkv_var,
      proj_w, proj_gamma, proj_beta, proj_mean, proj_var,
      wq, biasq, wp, biasp);

  // qkv GEMM (fused x transpose): grid.x = (b, ntile), grid.y = otile
  gemm_qkv<<<dim3(128, 4), 256, 0, stream>>>(x, wq, biasq, qkT, vbuf);

  dwconv_bn<<<dim3(C_, B_), 256, 0, stream>>>(
      vbuf, pe_w, pe_gamma, pe_beta, pe_mean, pe_var, posb);

  // attention: grid.x = bh (XCD affinity), grid.y = q-tile
  attn_mfma<<<dim3(128, 8), 256, 0, stream>>>(qkT, vbuf, posb, vattnT);

  gemm_proj<<<dim3(128, 2), 256, 0, stream>>>(vattnT, wp, biasp, out);
}